// Round 6
// baseline (240.080 us; speedup 1.0000x reference)
//
#include <hip/hip_runtime.h>
#include <hip/hip_bf16.h>

#define N_NODES 50000
#define KNB 16
#define FDIM 128
#define HDIM 128
#define ALPHA 0.3f
#define BN_EPS 1e-3f

typedef __bf16 v8bf __attribute__((ext_vector_type(8)));
typedef float v4f __attribute__((ext_vector_type(4)));
typedef unsigned short ushort_t;

__device__ __forceinline__ float blo(unsigned int u) {
    union { float f; unsigned int i; } x; x.i = u << 16; return x.f;
}
__device__ __forceinline__ float bhi(unsigned int u) {
    union { float f; unsigned int i; } x; x.i = u & 0xffff0000u; return x.f;
}

__device__ __forceinline__ unsigned short f2bf(float f) {
    union { float f; unsigned int u; } x;
    x.f = f;
    unsigned int r = x.u + 0x7fffu + ((x.u >> 16) & 1u);  // RNE
    return (unsigned short)(r >> 16);
}

// packed f32x2 -> bf16x2 (RNE)
__device__ __forceinline__ unsigned int pk2(float a, float b) {
    __hip_bfloat162 h = __float22bfloat162_rn(make_float2(a, b));
    union { __hip_bfloat162 h; unsigned int u; } r; r.h = h; return r.u;
}

__device__ __forceinline__ float lrelu(float x) { return x > 0.f ? x : ALPHA * x; }

__device__ __forceinline__ v8bf load8f(const float* p) {
    float4 A = ((const float4*)p)[0];
    float4 B = ((const float4*)p)[1];
    union { v8bf v; unsigned int u[4]; } r;
    r.u[0] = pk2(A.x, A.y); r.u[1] = pk2(A.z, A.w);
    r.u[2] = pk2(B.x, B.y); r.u[3] = pk2(B.z, B.w);
    return r.v;
}

// ---------------------------------------------------------------------------
// Kernel 0: convert + transpose weights to bf16 once.
// WT layout (ushort): [0) WqT 128x128 | [16384) WkT | [32768) WvT | [49152) W1T 128x256
// ---------------------------------------------------------------------------
__global__ __launch_bounds__(256) void prep_kernel(
    const float* __restrict__ Wq, const float* __restrict__ Wk,
    const float* __restrict__ Wv, const float* __restrict__ W1,
    ushort_t* __restrict__ WT)
{
    const int idx = blockIdx.x * 256 + threadIdx.x;
    if (idx < 16384) {
        int k = idx >> 7, n = idx & 127;
        WT[n * 128 + k] = f2bf(Wq[idx]);
    } else if (idx < 32768) {
        int i = idx - 16384; int k = i >> 7, n = i & 127;
        WT[16384 + n * 128 + k] = f2bf(Wk[i]);
    } else if (idx < 49152) {
        int i = idx - 32768; int k = i >> 7, n = i & 127;
        WT[32768 + n * 128 + k] = f2bf(Wv[i]);
    } else if (idx < 81920) {
        int i = idx - 49152; int k = i >> 7, n = i & 127;  // k in [0,256)
        WT[49152 + n * 256 + k] = f2bf(W1[i]);
    }
}

// ---------------------------------------------------------------------------
// Kernel A (R6: 64-row blocks, grid 782 — load-balance fix):
// R2-proven structure (swapped-operand MFMA => D^T, wave-private LDS staging,
// 1KB-linear copy-out), but each wave now owns 16 rows (single row-block):
// grid 391 was 1.53 blocks/CU (half the CUs ran 2 blocks => 2x latency-bound
// time). 782 blocks = 3.05/CU, acc halves (VGPR down => more waves/SIMD).
// ---------------------------------------------------------------------------
#define QSTRIDE 560   // bytes/row in Q staging tile (140 dwords: 2-way banks)
#define KVSTRIDE 528  // bytes/row in KV staging tile (132 dwords)
#define WTILE 9216    // per-wave LDS region (>= 16*560), 16B aligned

__global__ __launch_bounds__(256) void qkv_kernel(
    const float* __restrict__ E, const ushort_t* __restrict__ WT,
    const float* __restrict__ bq, const float* __restrict__ bk,
    const float* __restrict__ bv,
    float* __restrict__ Qo, ushort_t* __restrict__ KV)
{
    __shared__ char smem[4 * WTILE];

    const int tid  = threadIdx.x;
    const int wave = tid >> 6;
    const int lane = tid & 63;
    const int quad = lane >> 4;
    const int j    = lane & 15;
    const int row0 = blockIdx.x * 64 + wave * 16;

    char* const wbase = smem + wave * WTILE;

    const int ar = min(row0 + j, N_NODES - 1);

    v8bf af[4];
#pragma unroll
    for (int ks = 0; ks < 4; ++ks) {
        const int k0 = ks * 32 + quad * 8;
        af[ks] = load8f(E + (size_t)ar * FDIM + k0);
    }

    const float* biases[3] = {bq, bk, bv};

    for (int w = 0; w < 3; ++w) {
        const ushort_t* __restrict__ Wsrc = WT + w * 16384;

        v4f acc[8];
#pragma unroll
        for (int c = 0; c < 8; ++c) acc[c] = (v4f){0.f, 0.f, 0.f, 0.f};

#pragma unroll
        for (int ks = 0; ks < 4; ++ks) {
            const int k0 = ks * 32 + quad * 8;
            v8bf b[8];
#pragma unroll
            for (int c = 0; c < 8; ++c)
                b[c] = *(const v8bf*)(Wsrc + (c * 16 + j) * 128 + k0);
            // SWAPPED operands: D^T — lane (quad,j) holds row row0+j,
            // cols c*16+quad*4 .. +3 (4 consecutive columns).
#pragma unroll
            for (int c = 0; c < 8; ++c)
                acc[c] = __builtin_amdgcn_mfma_f32_16x16x32_bf16(b[c], af[ks], acc[c], 0, 0, 0);
        }

        const float* __restrict__ bias = biases[w];

        if (w == 0) {
            // ---- Q: stage f32 tile (16 rows x 512B) then 1KB-linear stores
#pragma unroll
            for (int c = 0; c < 8; ++c) {
                const float4 bb = ((const float4*)bias)[c * 4 + quad];
                v4f v = acc[c];
                v[0] = lrelu(v[0] + bb.x); v[1] = lrelu(v[1] + bb.y);
                v[2] = lrelu(v[2] + bb.z); v[3] = lrelu(v[3] + bb.w);
                *(v4f*)(wbase + j * QSTRIDE + (c * 16 + quad * 4) * 4) = v;
            }
#pragma unroll
            for (int t = 0; t < 8; ++t) {
                const int r  = 2 * t + (lane >> 5);
                const v4f v  = *(const v4f*)(wbase + r * QSTRIDE + (lane & 31) * 16);
                const int gr = row0 + r;
                if (gr < N_NODES)
                    *(v4f*)(Qo + (size_t)gr * HDIM + (lane & 31) * 4) = v;
            }
        } else {
            // ---- K (w=1) / V (w=2): pack bf16 into interleaved KV tile row
            const int voff = (w == 2) ? 256 : 0;  // V half at +256B in row
#pragma unroll
            for (int c = 0; c < 8; ++c) {
                const float4 bb = ((const float4*)bias)[c * 4 + quad];
                const v4f v = acc[c];
                uint2 u;
                u.x = pk2(lrelu(v[0] + bb.x), lrelu(v[1] + bb.y));
                u.y = pk2(lrelu(v[2] + bb.z), lrelu(v[3] + bb.w));
                *(uint2*)(wbase + j * KVSTRIDE + (c * 16 + quad * 4) * 2 + voff) = u;
            }
            if (w == 2) {
                // full 512B KV rows staged — 1KB-linear copy-out
#pragma unroll
                for (int t = 0; t < 8; ++t) {
                    const int r  = 2 * t + (lane >> 5);
                    const uint4 v = *(const uint4*)(wbase + r * KVSTRIDE + (lane & 31) * 16);
                    const int gr = row0 + r;
                    if (gr < N_NODES)   // guard: row 50000+ would smash WT in ws
                        *(uint4*)((char*)KV + (size_t)gr * 512 + (lane & 31) * 16) = v;
                }
            }
        }
    }
}

// ---------------------------------------------------------------------------
// Kernel B (R5-proven, unchanged — control this round): 2 nodes/wave, all
// 16 gathers preloaded. Pinned at ~59 µs by per-XCD compulsory L2 fill
// (FETCH 188 MB = 8 XCD x 23.5 MB) — byte-bound, not schedulable-away.
// ---------------------------------------------------------------------------
#define DOT8(qa, qb, kp) (qa.x*blo(kp.x) + qa.y*bhi(kp.x) + qa.z*blo(kp.y) + qa.w*bhi(kp.y) \
                        + qb.x*blo(kp.z) + qb.y*bhi(kp.z) + qb.z*blo(kp.w) + qb.w*bhi(kp.w))

__global__ __launch_bounds__(256) void attn_kernel(
    float* __restrict__ QP, const ushort_t* __restrict__ KV,
    const int* __restrict__ nbr)
{
    const int tid  = threadIdx.x;
    const int wave = tid >> 6;
    const int lane = tid & 63;
    const int grp  = lane >> 4;
    const int li   = lane & 15;
    const int n0 = __builtin_amdgcn_readfirstlane(blockIdx.x * 8 + wave * 2);
    const int n1 = n0 + 1;

    // per-lane q slices: elems li*8 .. +7 (32B); row shared by all 4 groups
    const float4* qr0 = (const float4*)(QP + (size_t)n0 * HDIM + li * 8);
    const float4 q0a = qr0[0], q0b = qr0[1];
    const float4* qr1 = (const float4*)(QP + (size_t)n1 * HDIM + li * 8);
    const float4 q1a = qr1[0], q1b = qr1[1];

    // neighbor ids: group g, round t -> neighbor t*4+g
    const int* nbA = nbr + n0 * KNB;   // uniform base -> scalar loads
    const int* nbB = nbr + n1 * KNB;
    int nidA[4], nidB[4];
#pragma unroll
    for (int t = 0; t < 4; ++t) {
        int a0 = nbA[t*4+0]; a0 = ((unsigned)a0 < (unsigned)N_NODES) ? a0 : 0;
        int a1 = nbA[t*4+1]; a1 = ((unsigned)a1 < (unsigned)N_NODES) ? a1 : 0;
        int a2 = nbA[t*4+2]; a2 = ((unsigned)a2 < (unsigned)N_NODES) ? a2 : 0;
        int a3 = nbA[t*4+3]; a3 = ((unsigned)a3 < (unsigned)N_NODES) ? a3 : 0;
        int va = a0;
        va = (grp == 1) ? a1 : va;
        va = (grp == 2) ? a2 : va;
        va = (grp == 3) ? a3 : va;
        nidA[t] = va;
        int b0 = nbB[t*4+0]; b0 = ((unsigned)b0 < (unsigned)N_NODES) ? b0 : 0;
        int b1 = nbB[t*4+1]; b1 = ((unsigned)b1 < (unsigned)N_NODES) ? b1 : 0;
        int b2 = nbB[t*4+2]; b2 = ((unsigned)b2 < (unsigned)N_NODES) ? b2 : 0;
        int b3 = nbB[t*4+3]; b3 = ((unsigned)b3 < (unsigned)N_NODES) ? b3 : 0;
        int vb = b0;
        vb = (grp == 1) ? b1 : vb;
        vb = (grp == 2) ? b2 : vb;
        vb = (grp == 3) ? b3 : vb;
        nidB[t] = vb;
    }

    const char* kvb = (const char*)KV;
    const size_t lo16 = (size_t)(li * 16);

    // ---- PRELOAD all 16 gathers (8 K + 8 V) — max memory-level parallelism
    uint4 kA[4], kB[4], vA[4], vB[4];
#pragma unroll
    for (int t = 0; t < 4; ++t) {
        kA[t] = *(const uint4*)(kvb + (size_t)nidA[t] * 512 + lo16);
        kB[t] = *(const uint4*)(kvb + (size_t)nidB[t] * 512 + lo16);
        vA[t] = *(const uint4*)(kvb + (size_t)nidA[t] * 512 + 256 + lo16);
        vB[t] = *(const uint4*)(kvb + (size_t)nidB[t] * 512 + 256 + lo16);
    }

    // ---- scores: 16-lane butterfly per node
    float sA[4], sB[4];
#pragma unroll
    for (int t = 0; t < 4; ++t) {
        sA[t] = DOT8(q0a, q0b, kA[t]);
        sB[t] = DOT8(q1a, q1b, kB[t]);
    }
#pragma unroll
    for (int off = 1; off <= 8; off <<= 1) {
#pragma unroll
        for (int t = 0; t < 4; ++t) {
            sA[t] += __shfl_xor(sA[t], off, 64);
            sB[t] += __shfl_xor(sB[t], off, 64);
        }
    }

    // ---- softmax across 16 neighbors (4 local + cross-group xor16/32)
    float mA = fmaxf(fmaxf(sA[0], sA[1]), fmaxf(sA[2], sA[3]));
    float mB = fmaxf(fmaxf(sB[0], sB[1]), fmaxf(sB[2], sB[3]));
    mA = fmaxf(mA, __shfl_xor(mA, 16, 64)); mB = fmaxf(mB, __shfl_xor(mB, 16, 64));
    mA = fmaxf(mA, __shfl_xor(mA, 32, 64)); mB = fmaxf(mB, __shfl_xor(mB, 32, 64));
    float aA[4], aB[4];
#pragma unroll
    for (int t = 0; t < 4; ++t) {
        aA[t] = __expf(sA[t] - mA);
        aB[t] = __expf(sB[t] - mB);
    }
    float sumA = aA[0] + aA[1] + aA[2] + aA[3];
    float sumB = aB[0] + aB[1] + aB[2] + aB[3];
    sumA += __shfl_xor(sumA, 16, 64); sumB += __shfl_xor(sumB, 16, 64);
    sumA += __shfl_xor(sumA, 32, 64); sumB += __shfl_xor(sumB, 32, 64);
    const float invA = 1.f / sumA, invB = 1.f / sumB;
#pragma unroll
    for (int t = 0; t < 4; ++t) { aA[t] *= invA; aB[t] *= invB; }

    // ---- PV: group-partials, then cross-group reduce (xor16/32)
    float pA[8] = {0,0,0,0,0,0,0,0}, pB[8] = {0,0,0,0,0,0,0,0};
#pragma unroll
    for (int t = 0; t < 4; ++t) {
        pA[0] += aA[t] * blo(vA[t].x); pA[1] += aA[t] * bhi(vA[t].x);
        pA[2] += aA[t] * blo(vA[t].y); pA[3] += aA[t] * bhi(vA[t].y);
        pA[4] += aA[t] * blo(vA[t].z); pA[5] += aA[t] * bhi(vA[t].z);
        pA[6] += aA[t] * blo(vA[t].w); pA[7] += aA[t] * bhi(vA[t].w);
        pB[0] += aB[t] * blo(vB[t].x); pB[1] += aB[t] * bhi(vB[t].x);
        pB[2] += aB[t] * blo(vB[t].y); pB[3] += aB[t] * bhi(vB[t].y);
        pB[4] += aB[t] * blo(vB[t].z); pB[5] += aB[t] * bhi(vB[t].z);
        pB[6] += aB[t] * blo(vB[t].w); pB[7] += aB[t] * bhi(vB[t].w);
    }
#pragma unroll
    for (int i = 0; i < 8; ++i) {
        pA[i] += __shfl_xor(pA[i], 16, 64); pB[i] += __shfl_xor(pB[i], 16, 64);
        pA[i] += __shfl_xor(pA[i], 32, 64); pB[i] += __shfl_xor(pB[i], 32, 64);
    }

    // grp0 stores node0's pooled row, grp1 stores node1's (values are
    // fully reduced in every lane; li indexes the 32B slice).
    if (grp == 0) {
        float4* out = (float4*)(QP + (size_t)n0 * HDIM + li * 8);
        out[0] = make_float4(pA[0], pA[1], pA[2], pA[3]);
        out[1] = make_float4(pA[4], pA[5], pA[6], pA[7]);
    } else if (grp == 1) {
        float4* out = (float4*)(QP + (size_t)n1 * HDIM + li * 8);
        out[0] = make_float4(pB[0], pB[1], pB[2], pB[3]);
        out[1] = make_float4(pB[4], pB[5], pB[6], pB[7]);
    }
}

// ---------------------------------------------------------------------------
// Kernel C (R6: 64-row blocks, grid 782 — load-balance fix):
// out = BN(rownorm(lrelu([E,pooled]@W1+b1))). R3-proven structure (LDS
// W-staging, swapped-operand MFMA, 16B vector stores), wave owns 16 rows.
// The barrier at the end of half=1 orders pooled reads before epilogue
// writes within a block; blocks touch only their own rows (clamped tail
// reads stay block-local, same reasoning as R0).
// ---------------------------------------------------------------------------
__global__ __launch_bounds__(256) void out_kernel(
    const float* __restrict__ E, const ushort_t* __restrict__ W1T,
    const float* __restrict__ b1,
    const float* __restrict__ gamma, const float* __restrict__ beta,
    const float* __restrict__ mmean, const float* __restrict__ mvar,
    float* __restrict__ OutP)   // pooled (in) + out (result)
{
    __shared__ ushort_t sW[128 * 136];

    const int tid  = threadIdx.x;
    const int wave = tid >> 6;
    const int lane = tid & 63;
    const int quad = lane >> 4;
    const int j    = lane & 15;
    const int row0 = blockIdx.x * 64 + wave * 16;

    const int ar = min(row0 + j, N_NODES - 1);

    v4f acc[8];
#pragma unroll
    for (int c = 0; c < 8; ++c) acc[c] = (v4f){0.f, 0.f, 0.f, 0.f};

    for (int half = 0; half < 2; ++half) {
        for (int i = tid; i < 2048; i += 256) {
            int n = i >> 4, kc = i & 15;
            *(uint4*)(&sW[n * 136 + kc * 8]) =
                *(const uint4*)(W1T + n * 256 + half * 128 + kc * 8);
        }
        __syncthreads();

        const float* Abase = (half == 0) ? E : (const float*)OutP;
#pragma unroll
        for (int ks = 0; ks < 4; ++ks) {
            const int k0 = ks * 32 + quad * 8;
            v8bf a0 = load8f(Abase + (size_t)ar * 128 + k0);
            v8bf b[8];
#pragma unroll
            for (int c = 0; c < 8; ++c)
                b[c] = *(const v8bf*)(&sW[(c * 16 + j) * 136 + k0]);
            // SWAPPED operands: D^T (lane (quad,j) -> row j, cols c*16+quad*4..+3)
#pragma unroll
            for (int c = 0; c < 8; ++c)
                acc[c] = __builtin_amdgcn_mfma_f32_16x16x32_bf16(b[c], a0, acc[c], 0, 0, 0);
        }
        __syncthreads();   // orders pooled reads before epilogue writes
    }

    // 1) bias + lrelu
#pragma unroll
    for (int c = 0; c < 8; ++c) {
        const float4 bb = ((const float4*)b1)[c * 4 + quad];
        acc[c][0] = lrelu(acc[c][0] + bb.x);
        acc[c][1] = lrelu(acc[c][1] + bb.y);
        acc[c][2] = lrelu(acc[c][2] + bb.z);
        acc[c][3] = lrelu(acc[c][3] + bb.w);
    }

    // 2) row norm (row = row0 + j): quad-partials, reduce over xor16/32
    float ss = 0.f;
#pragma unroll
    for (int c = 0; c < 8; ++c)
#pragma unroll
        for (int i = 0; i < 4; ++i) ss += acc[c][i] * acc[c][i];
    ss += __shfl_xor(ss, 16, 64);
    ss += __shfl_xor(ss, 32, 64);
    const float invn = 1.f / (sqrtf(ss) + 1e-6f);

    // 3) BN + 16B vector stores
    const int rw = row0 + j;
#pragma unroll
    for (int c = 0; c < 8; ++c) {
        const float4 g4 = ((const float4*)gamma)[c * 4 + quad];
        const float4 vv = ((const float4*)mvar )[c * 4 + quad];
        const float4 be = ((const float4*)beta )[c * 4 + quad];
        const float4 mm = ((const float4*)mmean)[c * 4 + quad];
        v4f sc4, sh4;
        sc4[0] = g4.x * rsqrtf(vv.x + BN_EPS); sh4[0] = be.x - mm.x * sc4[0];
        sc4[1] = g4.y * rsqrtf(vv.y + BN_EPS); sh4[1] = be.y - mm.y * sc4[1];
        sc4[2] = g4.z * rsqrtf(vv.z + BN_EPS); sh4[2] = be.z - mm.z * sc4[2];
        sc4[3] = g4.w * rsqrtf(vv.w + BN_EPS); sh4[3] = be.w - mm.w * sc4[3];
        const int colb = c * 16 + quad * 4;
        if (rw < N_NODES) {
            v4f o;
#pragma unroll
            for (int i = 0; i < 4; ++i) o[i] = acc[c][i] * invn * sc4[i] + sh4[i];
            *(v4f*)(OutP + (size_t)rw * HDIM + colb) = o;
        }
    }
}

extern "C" void kernel_launch(void* const* d_in, const int* in_sizes, int n_in,
                              void* d_out, int out_size, void* d_ws, size_t ws_size,
                              hipStream_t stream)
{
    const float* E     = (const float*)d_in[0];
    const int*   nbr   = (const int*)d_in[2];
    const float* Wq    = (const float*)d_in[3];
    const float* bq    = (const float*)d_in[4];
    const float* Wk    = (const float*)d_in[5];
    const float* bk    = (const float*)d_in[6];
    const float* Wv    = (const float*)d_in[7];
    const float* bv    = (const float*)d_in[8];
    const float* W1    = (const float*)d_in[9];
    const float* b1    = (const float*)d_in[10];
    const float* gam   = (const float*)d_in[11];
    const float* bet   = (const float*)d_in[12];
    const float* mmean = (const float*)d_in[13];
    const float* mvar  = (const float*)d_in[14];

    // ws: KV interleaved bf16 (25.6 MB) + WT bf16 (160 KB) = 25.76 MB total
    // (PROVEN budget — R7's 38.56 MB overflowed d_ws and corrupted the
    // harness's pristine buffers). Q (f32) then pooled (f32) share d_out.
    ushort_t* KV = (ushort_t*)d_ws;
    ushort_t* WT = KV + (size_t)N_NODES * 256;
    float* QP = (float*)d_out;

    const int gridA = (N_NODES + 63) / 64;  // 782 — 3.05 blocks/CU
    prep_kernel<<<320, 256, 0, stream>>>(Wq, Wk, Wv, W1, WT);
    qkv_kernel<<<gridA, 256, 0, stream>>>(E, WT, bq, bk, bv, QP, KV);
    attn_kernel<<<N_NODES / 8, 256, 0, stream>>>(QP, KV, nbr);
    out_kernel<<<gridA, 256, 0, stream>>>(E, WT + 49152, b1, gam, bet, mmean, mvar, QP);
}

// Round 7
// 211.620 us; speedup vs baseline: 1.1345x; 1.1345x over previous
//
#include <hip/hip_runtime.h>
#include <hip/hip_bf16.h>

#define N_NODES 50000
#define KNB 16
#define FDIM 128
#define HDIM 128
#define ALPHA 0.3f
#define BN_EPS 1e-3f

typedef __bf16 v8bf __attribute__((ext_vector_type(8)));
typedef float v4f __attribute__((ext_vector_type(4)));
typedef unsigned short ushort_t;

__device__ __forceinline__ float blo(unsigned int u) {
    union { float f; unsigned int i; } x; x.i = u << 16; return x.f;
}
__device__ __forceinline__ float bhi(unsigned int u) {
    union { float f; unsigned int i; } x; x.i = u & 0xffff0000u; return x.f;
}

__device__ __forceinline__ unsigned short f2bf(float f) {
    union { float f; unsigned int u; } x;
    x.f = f;
    unsigned int r = x.u + 0x7fffu + ((x.u >> 16) & 1u);  // RNE
    return (unsigned short)(r >> 16);
}

// packed f32x2 -> bf16x2 (RNE)
__device__ __forceinline__ unsigned int pk2(float a, float b) {
    __hip_bfloat162 h = __float22bfloat162_rn(make_float2(a, b));
    union { __hip_bfloat162 h; unsigned int u; } r; r.h = h; return r.u;
}

__device__ __forceinline__ float lrelu(float x) { return x > 0.f ? x : ALPHA * x; }

__device__ __forceinline__ v8bf load8f(const float* p) {
    float4 A = ((const float4*)p)[0];
    float4 B = ((const float4*)p)[1];
    union { v8bf v; unsigned int u[4]; } r;
    r.u[0] = pk2(A.x, A.y); r.u[1] = pk2(A.z, A.w);
    r.u[2] = pk2(B.x, B.y); r.u[3] = pk2(B.z, B.w);
    return r.v;
}

// ---------------------------------------------------------------------------
// Kernel 0: convert + transpose weights to bf16 once.
// WT layout (ushort): [0) WqT 128x128 | [16384) WkT | [32768) WvT | [49152) W1T 128x256
// ---------------------------------------------------------------------------
__global__ __launch_bounds__(256) void prep_kernel(
    const float* __restrict__ Wq, const float* __restrict__ Wk,
    const float* __restrict__ Wv, const float* __restrict__ W1,
    ushort_t* __restrict__ WT)
{
    const int idx = blockIdx.x * 256 + threadIdx.x;
    if (idx < 16384) {
        int k = idx >> 7, n = idx & 127;
        WT[n * 128 + k] = f2bf(Wq[idx]);
    } else if (idx < 32768) {
        int i = idx - 16384; int k = i >> 7, n = i & 127;
        WT[16384 + n * 128 + k] = f2bf(Wk[i]);
    } else if (idx < 49152) {
        int i = idx - 32768; int k = i >> 7, n = i & 127;
        WT[32768 + n * 128 + k] = f2bf(Wv[i]);
    } else if (idx < 81920) {
        int i = idx - 49152; int k = i >> 7, n = i & 127;  // k in [0,256)
        WT[49152 + n * 256 + k] = f2bf(W1[i]);
    }
}

// ---------------------------------------------------------------------------
// Kernel A (R2-EXACT — best-in-total measured config, 128-row blocks):
// operand-swapped MFMA (D^T) + wave-private LDS staging + 1KB-linear
// dwordx4 copy-out. Single block does Q,K,V; B frags direct from L2-hot WT.
// ---------------------------------------------------------------------------
#define QSTRIDE 560   // bytes/row in Q staging tile (140 dwords: 2-way banks)
#define KVSTRIDE 528  // bytes/row in KV staging tile (132 dwords)
#define WTILE 18432   // per-wave LDS region (>= 32*560), 16B aligned

__global__ __launch_bounds__(256) void qkv_kernel(
    const float* __restrict__ E, const ushort_t* __restrict__ WT,
    const float* __restrict__ bq, const float* __restrict__ bk,
    const float* __restrict__ bv,
    float* __restrict__ Qo, ushort_t* __restrict__ KV)
{
    __shared__ char smem[4 * WTILE];

    const int tid  = threadIdx.x;
    const int wave = tid >> 6;
    const int lane = tid & 63;
    const int quad = lane >> 4;
    const int j    = lane & 15;
    const int row0 = blockIdx.x * 128 + wave * 32;

    char* const wbase = smem + wave * WTILE;

    const int ar0 = min(row0 + j,      N_NODES - 1);
    const int ar1 = min(row0 + 16 + j, N_NODES - 1);

    v8bf a0f[4], a1f[4];
#pragma unroll
    for (int ks = 0; ks < 4; ++ks) {
        const int k0 = ks * 32 + quad * 8;
        a0f[ks] = load8f(E + (size_t)ar0 * FDIM + k0);
        a1f[ks] = load8f(E + (size_t)ar1 * FDIM + k0);
    }

    const float* biases[3] = {bq, bk, bv};

    for (int w = 0; w < 3; ++w) {
        const ushort_t* __restrict__ Wsrc = WT + w * 16384;

        v4f acc[2][8];
#pragma unroll
        for (int rb = 0; rb < 2; ++rb)
#pragma unroll
            for (int c = 0; c < 8; ++c) acc[rb][c] = (v4f){0.f, 0.f, 0.f, 0.f};

#pragma unroll
        for (int ks = 0; ks < 4; ++ks) {
            const int k0 = ks * 32 + quad * 8;
            v8bf b[8];
#pragma unroll
            for (int c = 0; c < 8; ++c)
                b[c] = *(const v8bf*)(Wsrc + (c * 16 + j) * 128 + k0);
            // SWAPPED operands: D^T — lane (quad,j) holds rows row0+rb*16+j,
            // cols c*16+quad*4 .. +3 (4 consecutive columns).
#pragma unroll
            for (int c = 0; c < 8; ++c) {
                acc[0][c] = __builtin_amdgcn_mfma_f32_16x16x32_bf16(b[c], a0f[ks], acc[0][c], 0, 0, 0);
                acc[1][c] = __builtin_amdgcn_mfma_f32_16x16x32_bf16(b[c], a1f[ks], acc[1][c], 0, 0, 0);
            }
        }

        const float* __restrict__ bias = biases[w];

        if (w == 0) {
            // ---- Q: stage f32 tile (32 rows x 512B) then 1KB-linear stores
#pragma unroll
            for (int rb = 0; rb < 2; ++rb)
#pragma unroll
                for (int c = 0; c < 8; ++c) {
                    const float4 bb = ((const float4*)bias)[c * 4 + quad];
                    v4f v = acc[rb][c];
                    v[0] = lrelu(v[0] + bb.x); v[1] = lrelu(v[1] + bb.y);
                    v[2] = lrelu(v[2] + bb.z); v[3] = lrelu(v[3] + bb.w);
                    *(v4f*)(wbase + (rb * 16 + j) * QSTRIDE + (c * 16 + quad * 4) * 4) = v;
                }
#pragma unroll
            for (int t = 0; t < 16; ++t) {
                const int r  = 2 * t + (lane >> 5);
                const v4f v  = *(const v4f*)(wbase + r * QSTRIDE + (lane & 31) * 16);
                const int gr = row0 + r;
                if (gr < N_NODES)
                    *(v4f*)(Qo + (size_t)gr * HDIM + (lane & 31) * 4) = v;
            }
        } else {
            // ---- K (w=1) / V (w=2): pack bf16 into interleaved KV tile row
            const int voff = (w == 2) ? 256 : 0;  // V half at +256B in row
#pragma unroll
            for (int rb = 0; rb < 2; ++rb)
#pragma unroll
                for (int c = 0; c < 8; ++c) {
                    const float4 bb = ((const float4*)bias)[c * 4 + quad];
                    const v4f v = acc[rb][c];
                    uint2 u;
                    u.x = pk2(lrelu(v[0] + bb.x), lrelu(v[1] + bb.y));
                    u.y = pk2(lrelu(v[2] + bb.z), lrelu(v[3] + bb.w));
                    *(uint2*)(wbase + (rb * 16 + j) * KVSTRIDE + (c * 16 + quad * 4) * 2 + voff) = u;
                }
            if (w == 2) {
                // full 512B KV rows staged — 1KB-linear copy-out
#pragma unroll
                for (int t = 0; t < 16; ++t) {
                    const int r  = 2 * t + (lane >> 5);
                    const uint4 v = *(const uint4*)(wbase + r * KVSTRIDE + (lane & 31) * 16);
                    const int gr = row0 + r;
                    if (gr < N_NODES)   // guard: row 50000+ would smash WT in ws
                        *(uint4*)((char*)KV + (size_t)gr * 512 + (lane & 31) * 16) = v;
                }
            }
        }
    }
}

// ---------------------------------------------------------------------------
// Kernel B (R5-EXACT — fastest isolated attn, 58.8 µs): 2 nodes/wave, all
// 16 gathers preloaded. Pinned by per-XCD compulsory L2 fill (FETCH 188 MB
// = 8 XCD x ~43K unique 512B rows) at the ~3.7 TB/s fill ceiling.
// ---------------------------------------------------------------------------
#define DOT8(qa, qb, kp) (qa.x*blo(kp.x) + qa.y*bhi(kp.x) + qa.z*blo(kp.y) + qa.w*bhi(kp.y) \
                        + qb.x*blo(kp.z) + qb.y*bhi(kp.z) + qb.z*blo(kp.w) + qb.w*bhi(kp.w))

__global__ __launch_bounds__(256) void attn_kernel(
    float* __restrict__ QP, const ushort_t* __restrict__ KV,
    const int* __restrict__ nbr)
{
    const int tid  = threadIdx.x;
    const int wave = tid >> 6;
    const int lane = tid & 63;
    const int grp  = lane >> 4;
    const int li   = lane & 15;
    const int n0 = __builtin_amdgcn_readfirstlane(blockIdx.x * 8 + wave * 2);
    const int n1 = n0 + 1;

    // per-lane q slices: elems li*8 .. +7 (32B); row shared by all 4 groups
    const float4* qr0 = (const float4*)(QP + (size_t)n0 * HDIM + li * 8);
    const float4 q0a = qr0[0], q0b = qr0[1];
    const float4* qr1 = (const float4*)(QP + (size_t)n1 * HDIM + li * 8);
    const float4 q1a = qr1[0], q1b = qr1[1];

    // neighbor ids: group g, round t -> neighbor t*4+g
    const int* nbA = nbr + n0 * KNB;   // uniform base -> scalar loads
    const int* nbB = nbr + n1 * KNB;
    int nidA[4], nidB[4];
#pragma unroll
    for (int t = 0; t < 4; ++t) {
        int a0 = nbA[t*4+0]; a0 = ((unsigned)a0 < (unsigned)N_NODES) ? a0 : 0;
        int a1 = nbA[t*4+1]; a1 = ((unsigned)a1 < (unsigned)N_NODES) ? a1 : 0;
        int a2 = nbA[t*4+2]; a2 = ((unsigned)a2 < (unsigned)N_NODES) ? a2 : 0;
        int a3 = nbA[t*4+3]; a3 = ((unsigned)a3 < (unsigned)N_NODES) ? a3 : 0;
        int va = a0;
        va = (grp == 1) ? a1 : va;
        va = (grp == 2) ? a2 : va;
        va = (grp == 3) ? a3 : va;
        nidA[t] = va;
        int b0 = nbB[t*4+0]; b0 = ((unsigned)b0 < (unsigned)N_NODES) ? b0 : 0;
        int b1 = nbB[t*4+1]; b1 = ((unsigned)b1 < (unsigned)N_NODES) ? b1 : 0;
        int b2 = nbB[t*4+2]; b2 = ((unsigned)b2 < (unsigned)N_NODES) ? b2 : 0;
        int b3 = nbB[t*4+3]; b3 = ((unsigned)b3 < (unsigned)N_NODES) ? b3 : 0;
        int vb = b0;
        vb = (grp == 1) ? b1 : vb;
        vb = (grp == 2) ? b2 : vb;
        vb = (grp == 3) ? b3 : vb;
        nidB[t] = vb;
    }

    const char* kvb = (const char*)KV;
    const size_t lo16 = (size_t)(li * 16);

    // ---- PRELOAD all 16 gathers (8 K + 8 V) — max memory-level parallelism
    uint4 kA[4], kB[4], vA[4], vB[4];
#pragma unroll
    for (int t = 0; t < 4; ++t) {
        kA[t] = *(const uint4*)(kvb + (size_t)nidA[t] * 512 + lo16);
        kB[t] = *(const uint4*)(kvb + (size_t)nidB[t] * 512 + lo16);
        vA[t] = *(const uint4*)(kvb + (size_t)nidA[t] * 512 + 256 + lo16);
        vB[t] = *(const uint4*)(kvb + (size_t)nidB[t] * 512 + 256 + lo16);
    }

    // ---- scores: 16-lane butterfly per node
    float sA[4], sB[4];
#pragma unroll
    for (int t = 0; t < 4; ++t) {
        sA[t] = DOT8(q0a, q0b, kA[t]);
        sB[t] = DOT8(q1a, q1b, kB[t]);
    }
#pragma unroll
    for (int off = 1; off <= 8; off <<= 1) {
#pragma unroll
        for (int t = 0; t < 4; ++t) {
            sA[t] += __shfl_xor(sA[t], off, 64);
            sB[t] += __shfl_xor(sB[t], off, 64);
        }
    }

    // ---- softmax across 16 neighbors (4 local + cross-group xor16/32)
    float mA = fmaxf(fmaxf(sA[0], sA[1]), fmaxf(sA[2], sA[3]));
    float mB = fmaxf(fmaxf(sB[0], sB[1]), fmaxf(sB[2], sB[3]));
    mA = fmaxf(mA, __shfl_xor(mA, 16, 64)); mB = fmaxf(mB, __shfl_xor(mB, 16, 64));
    mA = fmaxf(mA, __shfl_xor(mA, 32, 64)); mB = fmaxf(mB, __shfl_xor(mB, 32, 64));
    float aA[4], aB[4];
#pragma unroll
    for (int t = 0; t < 4; ++t) {
        aA[t] = __expf(sA[t] - mA);
        aB[t] = __expf(sB[t] - mB);
    }
    float sumA = aA[0] + aA[1] + aA[2] + aA[3];
    float sumB = aB[0] + aB[1] + aB[2] + aB[3];
    sumA += __shfl_xor(sumA, 16, 64); sumB += __shfl_xor(sumB, 16, 64);
    sumA += __shfl_xor(sumA, 32, 64); sumB += __shfl_xor(sumB, 32, 64);
    const float invA = 1.f / sumA, invB = 1.f / sumB;
#pragma unroll
    for (int t = 0; t < 4; ++t) { aA[t] *= invA; aB[t] *= invB; }

    // ---- PV: group-partials, then cross-group reduce (xor16/32)
    float pA[8] = {0,0,0,0,0,0,0,0}, pB[8] = {0,0,0,0,0,0,0,0};
#pragma unroll
    for (int t = 0; t < 4; ++t) {
        pA[0] += aA[t] * blo(vA[t].x); pA[1] += aA[t] * bhi(vA[t].x);
        pA[2] += aA[t] * blo(vA[t].y); pA[3] += aA[t] * bhi(vA[t].y);
        pA[4] += aA[t] * blo(vA[t].z); pA[5] += aA[t] * bhi(vA[t].z);
        pA[6] += aA[t] * blo(vA[t].w); pA[7] += aA[t] * bhi(vA[t].w);
        pB[0] += aB[t] * blo(vB[t].x); pB[1] += aB[t] * bhi(vB[t].x);
        pB[2] += aB[t] * blo(vB[t].y); pB[3] += aB[t] * bhi(vB[t].y);
        pB[4] += aB[t] * blo(vB[t].z); pB[5] += aB[t] * bhi(vB[t].z);
        pB[6] += aB[t] * blo(vB[t].w); pB[7] += aB[t] * bhi(vB[t].w);
    }
#pragma unroll
    for (int i = 0; i < 8; ++i) {
        pA[i] += __shfl_xor(pA[i], 16, 64); pB[i] += __shfl_xor(pB[i], 16, 64);
        pA[i] += __shfl_xor(pA[i], 32, 64); pB[i] += __shfl_xor(pB[i], 32, 64);
    }

    // grp0 stores node0's pooled row, grp1 stores node1's (values are
    // fully reduced in every lane; li indexes the 32B slice).
    if (grp == 0) {
        float4* out = (float4*)(QP + (size_t)n0 * HDIM + li * 8);
        out[0] = make_float4(pA[0], pA[1], pA[2], pA[3]);
        out[1] = make_float4(pA[4], pA[5], pA[6], pA[7]);
    } else if (grp == 1) {
        float4* out = (float4*)(QP + (size_t)n1 * HDIM + li * 8);
        out[0] = make_float4(pB[0], pB[1], pB[2], pB[3]);
        out[1] = make_float4(pB[4], pB[5], pB[6], pB[7]);
    }
}

// ---------------------------------------------------------------------------
// Kernel C (R2-EXACT, R0-style — best-in-total measured):
// out = BN(rownorm(lrelu([E,pooled]@W1+b1))). pooled (f32) lives in d_out;
// result overwrites d_out. The barrier at the end of half=1 orders all
// pooled reads before any epilogue write within a block; blocks read/write
// only their own row range — no cross-block hazard.
// (Cross-round accounting R2 vs R3/R5: this epilogue beat the vector-store
// variant by ~4-6 µs in total — keep it.)
// ---------------------------------------------------------------------------
__global__ __launch_bounds__(256) void out_kernel(
    const float* __restrict__ E, const ushort_t* __restrict__ W1T,
    const float* __restrict__ b1,
    const float* __restrict__ gamma, const float* __restrict__ beta,
    const float* __restrict__ mmean, const float* __restrict__ mvar,
    float* __restrict__ OutP)   // pooled (in) + out (result)
{
    __shared__ ushort_t sW[128 * 136];

    const int tid  = threadIdx.x;
    const int wave = tid >> 6;
    const int lane = tid & 63;
    const int quad = lane >> 4;
    const int j    = lane & 15;
    const int row0 = blockIdx.x * 128 + wave * 32;

    const int ar0 = min(row0 + j,      N_NODES - 1);
    const int ar1 = min(row0 + 16 + j, N_NODES - 1);

    v4f acc[2][8];
#pragma unroll
    for (int rb = 0; rb < 2; ++rb)
#pragma unroll
        for (int c = 0; c < 8; ++c) acc[rb][c] = (v4f){0.f, 0.f, 0.f, 0.f};

    for (int half = 0; half < 2; ++half) {
        for (int i = tid; i < 2048; i += 256) {
            int n = i >> 4, kc = i & 15;
            *(uint4*)(&sW[n * 136 + kc * 8]) =
                *(const uint4*)(W1T + n * 256 + half * 128 + kc * 8);
        }
        __syncthreads();

        const float* Abase = (half == 0) ? E : (const float*)OutP;
#pragma unroll
        for (int ks = 0; ks < 4; ++ks) {
            const int k0 = ks * 32 + quad * 8;
            v8bf a0 = load8f(Abase + (size_t)ar0 * 128 + k0);
            v8bf a1 = load8f(Abase + (size_t)ar1 * 128 + k0);
            v8bf b[8];
#pragma unroll
            for (int c = 0; c < 8; ++c)
                b[c] = *(const v8bf*)(&sW[(c * 16 + j) * 136 + k0]);
#pragma unroll
            for (int c = 0; c < 8; ++c) {
                acc[0][c] = __builtin_amdgcn_mfma_f32_16x16x32_bf16(a0, b[c], acc[0][c], 0, 0, 0);
                acc[1][c] = __builtin_amdgcn_mfma_f32_16x16x32_bf16(a1, b[c], acc[1][c], 0, 0, 0);
            }
        }
        __syncthreads();   // orders pooled reads before epilogue writes
    }

    float scale_[8], shift_[8], bias_[8];
#pragma unroll
    for (int c = 0; c < 8; ++c) {
        const int col = c * 16 + j;
        const float sc = gamma[col] * rsqrtf(mvar[col] + BN_EPS);
        scale_[c] = sc;
        shift_[c] = beta[col] - mmean[col] * sc;
        bias_[c]  = b1[col];
    }

#pragma unroll
    for (int rb = 0; rb < 2; ++rb)
#pragma unroll
        for (int c = 0; c < 8; ++c)
#pragma unroll
            for (int i = 0; i < 4; ++i)
                acc[rb][c][i] = lrelu(acc[rb][c][i] + bias_[c]);

#pragma unroll
    for (int rb = 0; rb < 2; ++rb) {
#pragma unroll
        for (int i = 0; i < 4; ++i) {
            float ss = 0.f;
#pragma unroll
            for (int c = 0; c < 8; ++c) ss += acc[rb][c][i] * acc[rb][c][i];
            ss += __shfl_xor(ss, 1, 64);
            ss += __shfl_xor(ss, 2, 64);
            ss += __shfl_xor(ss, 4, 64);
            ss += __shfl_xor(ss, 8, 64);
            const float invn = 1.f / (sqrtf(ss) + 1e-6f);
            const int r = row0 + rb * 16 + quad * 4 + i;
            if (r < N_NODES) {
#pragma unroll
                for (int c = 0; c < 8; ++c)
                    OutP[(size_t)r * HDIM + c * 16 + j] =
                        acc[rb][c][i] * invn * scale_[c] + shift_[c];
            }
        }
    }
}

extern "C" void kernel_launch(void* const* d_in, const int* in_sizes, int n_in,
                              void* d_out, int out_size, void* d_ws, size_t ws_size,
                              hipStream_t stream)
{
    const float* E     = (const float*)d_in[0];
    const int*   nbr   = (const int*)d_in[2];
    const float* Wq    = (const float*)d_in[3];
    const float* bq    = (const float*)d_in[4];
    const float* Wk    = (const float*)d_in[5];
    const float* bk    = (const float*)d_in[6];
    const float* Wv    = (const float*)d_in[7];
    const float* bv    = (const float*)d_in[8];
    const float* W1    = (const float*)d_in[9];
    const float* b1    = (const float*)d_in[10];
    const float* gam   = (const float*)d_in[11];
    const float* bet   = (const float*)d_in[12];
    const float* mmean = (const float*)d_in[13];
    const float* mvar  = (const float*)d_in[14];

    // ws: KV interleaved bf16 (25.6 MB) + WT bf16 (160 KB) = 25.76 MB total
    // (PROVEN budget). Q (f32) then pooled (f32) share d_out.
    ushort_t* KV = (ushort_t*)d_ws;
    ushort_t* WT = KV + (size_t)N_NODES * 256;
    float* QP = (float*)d_out;

    const int gridA = (N_NODES + 127) / 128;  // 391
    prep_kernel<<<320, 256, 0, stream>>>(Wq, Wk, Wv, W1, WT);
    qkv_kernel<<<gridA, 256, 0, stream>>>(E, WT, bq, bk, bv, QP, KV);
    attn_kernel<<<N_NODES / 8, 256, 0, stream>>>(QP, KV, nbr);
    out_kernel<<<gridA, 256, 0, stream>>>(E, WT + 49152, b1, gam, bet, mmean, mvar, QP);
}